// Round 14
// baseline (126.092 us; speedup 1.0000x reference)
//
#include <hip/hip_runtime.h>

#define PS 32
#define NPIX (PS * PS)
#define NB 36
#define WPB 4        // waves (patches in flight) per block
#define HCOL 64      // one exclusive histogram column per lane
#define HROWS 37     // 36 bins + pad row 36 (flagged dummy writes land there)
#define HWORDS (HROWS * HCOL)   // 2368 words per wave
#define NBLOCKS 1024 // 4 blocks/CU exactly; each wave strides over 16 patches

typedef float v2f __attribute__((ext_vector_type(2)));

// ---------------------------------------------------------------------------
// Init kernel: gk10[p] = float32(10 * CircularGaussKernel(32)) computed in f64.
// (Unchanged from rounds 1-13 — proven bit-exact.)
// ---------------------------------------------------------------------------
__global__ __launch_bounds__(256) void gk_init_kernel(float* __restrict__ gk10) {
    __shared__ double red[256];
    const int tid = threadIdx.x;
    const double delta = 32.0 / 31.0;       // numpy linspace step, f64
    const double sigma2 = 0.9 * 256.0;      // 0.9 * half^2, f64

    double kv[4];
    double s = 0.0;
#pragma unroll
    for (int j = 0; j < 4; ++j) {
        int p = tid * 4 + j;
        int r = p >> 5, c = p & 31;
        double xr = (r == 31) ? 16.0 : ((double)r * delta + (-16.0));
        double xc = (c == 31) ? 16.0 : ((double)c * delta + (-16.0));
        double d2 = xc * xc + xr * xr;
        kv[j] = exp(-d2 / sigma2);
        s += kv[j];
    }
    red[tid] = s;
    __syncthreads();
    for (int off = 128; off > 0; off >>= 1) {
        if (tid < off) red[tid] += red[tid + off];
        __syncthreads();
    }
    double sum = red[0];
#pragma unroll
    for (int j = 0; j < 4; ++j) {
        int p = tid * 4 + j;
        gk10[p] = __fmul_rn(10.0f, (float)(kv[j] / sum));
    }
}

// ---------------------------------------------------------------------------
// Cold path: exact f64 recompute of one flagged bin-boundary pixel.
// (Reference op order verbatim, rounds 1-13 proven.)
// ---------------------------------------------------------------------------
__device__ __attribute__((noinline))
void fix_pixel(float lv, float rv, float uv, float dv, float gk, float* col) {
    const float PI_F    = 3.14159265358979323846f;
    const float TWOPI_F = 6.28318530717958647692f;
    float gx = __fmul_rn(0.5f, __fsub_rn(lv, rv));
    float gy = __fmul_rn(0.5f, __fsub_rn(uv, dv));
    float s2 = __fadd_rn(__fadd_rn(__fmul_rn(gx, gx), __fmul_rn(gy, gy)), 1e-10f);
    float mag = __fmul_rn(__fsqrt_rn(s2), gk);

    float ori  = (float)atan2((double)gy, (double)gx);  // correctly-rounded f32
    float obig = __fdiv_rn(__fmul_rn(36.0f, __fadd_rn(ori, PI_F)), TWOPI_F);
    float bo0f = floorf(obig);
    float wo1  = __fsub_rn(obig, bo0f);
    int bo = (int)bo0f;
    if (bo >= NB) bo -= NB;
    float wo0 = __fmul_rn(__fsub_rn(1.0f, wo1), mag);
    col[bo * HCOL] += wo0;
}

// ---------------------------------------------------------------------------
// Main kernel: PERSISTENT waves, ONE PATCH PER WAVE PER ITERATION, zero LDS
// atomics, no LDS tile, branch-free hot loop (R12 math verbatim). Next
// patch's global loads are issued BEFORE the current hot loop so the ~600-900
// cycle HBM/L2 latency hides under ~1400 cycles of guaranteed VALU work.
// Gaussian weights loaded once per wave. DS-FIFO per-wave ordering makes the
// zero -> RMW -> reduce -> (next) zero sequence safe without barriers.
// ---------------------------------------------------------------------------
__global__ __launch_bounds__(256) void orient_kernel(const float* __restrict__ x,
                                                     const float* __restrict__ gk10,
                                                     float* __restrict__ out,
                                                     int B) {
#pragma clang fp contract(off)
    const float PI_F    = 3.14159265358979323846f;   // 0x40490FDB
    const float TWOPI_F = 6.28318530717958647692f;   // 0x40C90FDB

    __shared__ __align__(16) float hist[WPB][HWORDS];

    const int tid = threadIdx.x;
    const int w = tid >> 6;          // wave id within block
    const int l = tid & 63;          // lane within wave
    const int stride = gridDim.x * WPB;

    float* hw = hist[w];
    float* mycol = hw + l;

    const int sr = l >> 3;           // subtile row 0..7
    const int sc = l & 7;            // subtile col 0..7
    const int laneOff = (sr * 4) * PS + sc * 4;

    // ---- Gaussian weights: loaded ONCE per wave (same for all patches)
    float g[4][4];
    {
        const float* gb = gk10 + laneOff;
#pragma unroll
        for (int k = 0; k < 4; ++k) {
            float4 gq = *reinterpret_cast<const float4*>(gb + k * PS);
            g[k][0] = gq.x; g[k][1] = gq.y; g[k][2] = gq.z; g[k][3] = gq.w;
        }
    }

    int patch = blockIdx.x * WPB + w;
    if (patch >= B) return;

    // ---- Prologue: prefetch first patch
    float4 nxt[4];
    {
        const float* xb = x + (size_t)patch * NPIX + laneOff;
#pragma unroll
        for (int k = 0; k < 4; ++k)
            nxt[k] = *reinterpret_cast<const float4*>(xb + k * PS);
    }

    const float BINSCALE = 5.72957795130823208768f;  // 18/pi

    for (; patch < B; patch += stride) {
        // ---- Zero hist rows 0..35 (2304 words = 9 float4/lane); pad row 36
        // is write-only garbage. Independent of in-flight loads.
        {
            float4 z4 = make_float4(0.0f, 0.0f, 0.0f, 0.0f);
            float4* hz = reinterpret_cast<float4*>(hw);
#pragma unroll
            for (int p = 0; p < 9; ++p) hz[p * 64 + l] = z4;
        }

        // ---- Take current patch; issue NEXT patch's loads (fly during compute)
        float s[4][4];
#pragma unroll
        for (int k = 0; k < 4; ++k) {
            s[k][0] = nxt[k].x; s[k][1] = nxt[k].y;
            s[k][2] = nxt[k].z; s[k][3] = nxt[k].w;
        }
        const int np = patch + stride;
        if (np < B) {
            const float* xb = x + (size_t)np * NPIX + laneOff;
#pragma unroll
            for (int k = 0; k < 4; ++k)
                nxt[k] = *reinterpret_cast<const float4*>(xb + k * PS);
        }

        // ---- Halo exchange via lane shuffles; border replicate via cndmask
        const int upL = (sr > 0) ? (l - 8) : l;
        const int dnL = (sr < 7) ? (l + 8) : l;
        const int lfL = (sc > 0) ? (l - 1) : l;
        const int rtL = (sc < 7) ? (l + 1) : l;
        float Uh[4], Dh[4], Lh[4], Rh[4];
#pragma unroll
        for (int j = 0; j < 4; ++j) {
            float tu = __shfl(s[3][j], upL, 64);
            float td = __shfl(s[0][j], dnL, 64);
            Uh[j] = (sr == 0) ? s[0][j] : tu;
            Dh[j] = (sr == 7) ? s[3][j] : td;
        }
#pragma unroll
        for (int k = 0; k < 4; ++k) {
            float tl = __shfl(s[k][3], lfL, 64);
            float tr = __shfl(s[k][0], rtL, 64);
            Lh[k] = (sc == 0) ? s[k][0] : tl;
            Rh[k] = (sc == 7) ? s[k][3] : tr;
        }

        // ---- Branch-free hot loop: 16 pixels (R12 math verbatim; pad row
        // replaces the min clamp — flagged/over-range pixels write row 36).
        unsigned int badbits = 0;
#pragma unroll
        for (int k = 0; k < 4; ++k) {
#pragma unroll
            for (int j = 0; j < 4; ++j) {
                float lv = (j == 0) ? Lh[k] : s[k][j - 1];
                float rv = (j == 3) ? Rh[k] : s[k][j + 1];
                float uv = (k == 0) ? Uh[j] : s[k - 1][j];
                float dv = (k == 3) ? Dh[j] : s[k + 1][j];

                float dx = __fsub_rn(lv, rv);            // 2*gx
                float dy = __fsub_rn(uv, dv);            // 2*gy
                float t1 = fmaf(dy, dy, __fmul_rn(dx, dx));
                float s2 = fmaf(t1, 0.25f, 1e-10f);      // exact power-2 scale
                float mag = __fmul_rn(__fsqrt_rn(s2), g[k][j]);

                float ax = fabsf(dx), ay = fabsf(dy);
                float mn = fminf(ax, ay);
                float mx = fmaxf(fmaxf(ax, ay), 1.17549435e-38f);   // v_max3
                float rr = mn * __builtin_amdgcn_rcpf(mx);   // ~1 ulp, scale-inv
                float t  = rr * rr;
                float u = 0.00282363896258175373077393f;     // SLEEF deg-17 odd
                u = fmaf(u, t, -0.0159569028764963150024414f);
                u = fmaf(u, t,  0.0425049886107444763183594f);
                u = fmaf(u, t, -0.0748900920152664184570312f);
                u = fmaf(u, t,  0.106347933411598205566406f);
                u = fmaf(u, t, -0.142027363181114196777344f);
                u = fmaf(u, t,  0.199926957488059997558594f);
                u = fmaf(u, t, -0.333331018686294555664062f);
                float at  = fmaf(rr * t, u, rr);             // atan(rr), [0,pi/4]
                float atb = at * BINSCALE;                   // bins, [0, 4.5]

                // Quadrant fold (gx,gy never -0.0): a9 -> a18 -> copysign -> +18
                float a9  = (ay > ax)   ? __fsub_rn(9.0f,  atb) : atb;
                float a18 = (dx < 0.0f) ? __fsub_rn(18.0f, a9)  : a9;
                float as  = copysignf(a18, dy);              // v_bfi
                float obig = __fadd_rn(as, 18.0f);           // [0, 36]
                float wo1  = __builtin_amdgcn_fractf(obig);  // obig - floor
                unsigned bo = (unsigned)obig;                // 0..36 (36 = pad)

                bool bad = fabsf(__fsub_rn(wo1, 0.5f)) >= 0.49998f;
                float wo0 = fmaf(-wo1, mag, mag);            // (1-wo1)*mag, 1 ulp
                wo0 = bad ? 0.0f : wo0;                      // flagged: no-op add
                mycol[bo * HCOL] += wo0;                     // exclusive LDS RMW
                badbits |= bad ? (1u << (k * 4 + j)) : 0u;
            }
        }

        // ---- Rare exact f64 fixup (ballot-guarded; operands live in regs)
        if (__ballot(badbits != 0)) {
#pragma unroll
            for (int k = 0; k < 4; ++k) {
#pragma unroll
                for (int j = 0; j < 4; ++j) {
                    if (badbits & (1u << (k * 4 + j))) {
                        float lv = (j == 0) ? Lh[k] : s[k][j - 1];
                        float rv = (j == 3) ? Rh[k] : s[k][j + 1];
                        float uv = (k == 0) ? Uh[j] : s[k - 1][j];
                        float dv = (k == 3) ? Dh[j] : s[k + 1][j];
                        fix_pixel(lv, rv, uv, dv, g[k][j], mycol);
                    }
                }
            }
        }
        asm volatile("s_waitcnt lgkmcnt(0)" ::: "memory");

        // ---- Reduction (R12-proven rotated b64, + packed accumulate):
        // lane b (<36) sums its 64-word row; banks 2*(b+k)%32 ~ free 2-way.
        float hval = 0.0f;
        if (l < NB) {
            const float2* row2 = reinterpret_cast<const float2*>(hw + l * HCOL);
            v2f tot2 = {0.0f, 0.0f};
#pragma unroll
            for (int k = 0; k < 32; ++k) {
                float2 a = row2[(k + l) & 31];
                v2f av = {a.x, a.y};
                tot2 = tot2 + av;                 // v_pk_add_f32
            }
            float tot = tot2.x + tot2.y;
            hval = __fmul_rn(tot, 1.0f / 1024.0f);   // exact power-of-2 scale
        }

        // ---- Smoothing via lane shuffles (zero pad; lane 36 holds 0)
        float hm = __shfl_up(hval, 1, 64);
        if (l == 0) hm = 0.0f;
        float hp = __shfl_down(hval, 1, 64);
        float sm = 0.0f;
        if (l < NB) {
            sm = __fadd_rn(__fadd_rn(__fmul_rn(0.33f, hm), __fmul_rn(0.34f, hval)),
                           __fmul_rn(0.33f, hp));
        }

        // ---- Argmax: f32 max butterfly + ballot + ffs (first-wins: lowest lane)
        float mv = sm;
#pragma unroll
        for (int off = 32; off > 0; off >>= 1) {
            float o = __shfl_xor(mv, off, 64);
            mv = fmaxf(mv, o);
        }
        unsigned long long msk = __ballot(sm == mv);

        if (l == 0) {
            int bi = __ffsll(msk) - 1;
            float t2 = __fdiv_rn(__fmul_rn(TWOPI_F, (float)bi), 36.0f);
            out[patch] = __fsub_rn(PI_F, t2);
        }
        // Reduction reads were issued before next iteration's zero writes;
        // per-wave DS FIFO ordering keeps them correct without a barrier.
    }
}

extern "C" void kernel_launch(void* const* d_in, const int* in_sizes, int n_in,
                              void* d_out, int out_size, void* d_ws, size_t ws_size,
                              hipStream_t stream) {
    const float* x = (const float*)d_in[0];
    float* out = (float*)d_out;
    float* gk10 = (float*)d_ws;   // 1024 floats = 4 KB scratch

    const int B = in_sizes[0] / NPIX;

    int blocks = NBLOCKS;                      // 4 blocks/CU exactly
    int maxb   = (B + WPB - 1) / WPB;
    if (blocks > maxb) blocks = maxb;
    if (blocks < 1) blocks = 1;

    gk_init_kernel<<<1, 256, 0, stream>>>(gk10);
    orient_kernel<<<blocks, 256, 0, stream>>>(x, gk10, out, B);
}

// Round 15
// 103.052 us; speedup vs baseline: 1.2236x; 1.2236x over previous
//
#include <hip/hip_runtime.h>

#define PS 32
#define NPIX (PS * PS)
#define NB 36
#define WPB 4        // waves (patches) per block
#define HCOL 64      // one exclusive histogram column per lane
#define HROWS 37     // 36 bins + pad row 36 (flagged dummy writes land there)
#define HWORDS (HROWS * HCOL)   // 2368 words per wave

typedef float v2f __attribute__((ext_vector_type(2)));

// ---------------------------------------------------------------------------
// Init kernel: gk10[p] = float32(10 * CircularGaussKernel(32)) computed in f64.
// (Unchanged from rounds 1-14 — proven bit-exact.)
// ---------------------------------------------------------------------------
__global__ __launch_bounds__(256) void gk_init_kernel(float* __restrict__ gk10) {
    __shared__ double red[256];
    const int tid = threadIdx.x;
    const double delta = 32.0 / 31.0;       // numpy linspace step, f64
    const double sigma2 = 0.9 * 256.0;      // 0.9 * half^2, f64

    double kv[4];
    double s = 0.0;
#pragma unroll
    for (int j = 0; j < 4; ++j) {
        int p = tid * 4 + j;
        int r = p >> 5, c = p & 31;
        double xr = (r == 31) ? 16.0 : ((double)r * delta + (-16.0));
        double xc = (c == 31) ? 16.0 : ((double)c * delta + (-16.0));
        double d2 = xc * xc + xr * xr;
        kv[j] = exp(-d2 / sigma2);
        s += kv[j];
    }
    red[tid] = s;
    __syncthreads();
    for (int off = 128; off > 0; off >>= 1) {
        if (tid < off) red[tid] += red[tid + off];
        __syncthreads();
    }
    double sum = red[0];
#pragma unroll
    for (int j = 0; j < 4; ++j) {
        int p = tid * 4 + j;
        gk10[p] = __fmul_rn(10.0f, (float)(kv[j] / sum));
    }
}

// ---------------------------------------------------------------------------
// Cold path: exact f64 recompute of one flagged bin-boundary pixel.
// (Reference op order verbatim, rounds 1-14 proven.)
// ---------------------------------------------------------------------------
__device__ __attribute__((noinline))
void fix_pixel(float lv, float rv, float uv, float dv, float gk, float* col) {
    const float PI_F    = 3.14159265358979323846f;
    const float TWOPI_F = 6.28318530717958647692f;
    float gx = __fmul_rn(0.5f, __fsub_rn(lv, rv));
    float gy = __fmul_rn(0.5f, __fsub_rn(uv, dv));
    float s2 = __fadd_rn(__fadd_rn(__fmul_rn(gx, gx), __fmul_rn(gy, gy)), 1e-10f);
    float mag = __fmul_rn(__fsqrt_rn(s2), gk);

    float ori  = (float)atan2((double)gy, (double)gx);  // correctly-rounded f32
    float obig = __fdiv_rn(__fmul_rn(36.0f, __fadd_rn(ori, PI_F)), TWOPI_F);
    float bo0f = floorf(obig);
    float wo1  = __fsub_rn(obig, bo0f);
    int bo = (int)bo0f;
    if (bo >= NB) bo -= NB;
    float wo0 = __fmul_rn(__fsub_rn(1.0f, wo1), mag);
    col[bo * HCOL] += wo0;
}

// ---------------------------------------------------------------------------
// Main kernel: ONE WAVE PER PATCH (non-persistent — R14 proved persistence
// hurts), zero LDS atomics, no LDS tile, branch-free hot loop (R12 math
// verbatim). This round's cuts vs R12: pad row 36 replaces the per-pixel
// min_u32 clamp; reduction accumulates via v_pk_add_f32.
// ---------------------------------------------------------------------------
__global__ __launch_bounds__(256) void orient_kernel(const float* __restrict__ x,
                                                     const float* __restrict__ gk10,
                                                     float* __restrict__ out) {
#pragma clang fp contract(off)
    const float PI_F    = 3.14159265358979323846f;   // 0x40490FDB
    const float TWOPI_F = 6.28318530717958647692f;   // 0x40C90FDB

    __shared__ __align__(16) float hist[WPB][HWORDS];

    const int tid = threadIdx.x;
    const int w = tid >> 6;          // wave id within block
    const int l = tid & 63;          // lane within wave
    const int patch = blockIdx.x * WPB + w;

    float* hw = hist[w];

    const int sr = l >> 3;           // subtile row 0..7
    const int sc = l & 7;            // subtile col 0..7

    // ---- Global loads: lane's 4x4 subtile + matching gaussian weights
    const float* xb = x + (size_t)patch * NPIX + (sr * 4) * PS + sc * 4;
    const float* gb = gk10 + (sr * 4) * PS + sc * 4;
    float4 sq[4], gq[4];
#pragma unroll
    for (int k = 0; k < 4; ++k) {
        sq[k] = *reinterpret_cast<const float4*>(xb + k * PS);
        gq[k] = *reinterpret_cast<const float4*>(gb + k * PS);
    }

    // ---- Zero hist rows 0..35 (2304 words = 9 float4/lane); pad row 36 is
    // write-only garbage (never read), no need to zero.
    {
        float4 z4 = make_float4(0.0f, 0.0f, 0.0f, 0.0f);
        float4* hz = reinterpret_cast<float4*>(hw);
#pragma unroll
        for (int p = 0; p < 9; ++p) hz[p * 64 + l] = z4;
    }

    // Unpack to scalar arrays (register file)
    float s[4][4], g[4][4];
#pragma unroll
    for (int k = 0; k < 4; ++k) {
        s[k][0] = sq[k].x; s[k][1] = sq[k].y; s[k][2] = sq[k].z; s[k][3] = sq[k].w;
        g[k][0] = gq[k].x; g[k][1] = gq[k].y; g[k][2] = gq[k].z; g[k][3] = gq[k].w;
    }

    // ---- Halo exchange via lane shuffles; border replicate via cndmask
    const int upL = (sr > 0) ? (l - 8) : l;
    const int dnL = (sr < 7) ? (l + 8) : l;
    const int lfL = (sc > 0) ? (l - 1) : l;
    const int rtL = (sc < 7) ? (l + 1) : l;
    float Uh[4], Dh[4], Lh[4], Rh[4];
#pragma unroll
    for (int j = 0; j < 4; ++j) {
        float tu = __shfl(s[3][j], upL, 64);
        float td = __shfl(s[0][j], dnL, 64);
        Uh[j] = (sr == 0) ? s[0][j] : tu;
        Dh[j] = (sr == 7) ? s[3][j] : td;
    }
#pragma unroll
    for (int k = 0; k < 4; ++k) {
        float tl = __shfl(s[k][3], lfL, 64);
        float tr = __shfl(s[k][0], rtL, 64);
        Lh[k] = (sc == 0) ? s[k][0] : tl;
        Rh[k] = (sc == 7) ? s[k][3] : tr;
    }

    // ---- Branch-free hot loop: 16 pixels, all operands in registers.
    // (R12 math verbatim — proven absmax 0.0; pad row replaces min clamp.)
    unsigned int badbits = 0;
    float* mycol = hw + l;
    const float BINSCALE = 5.72957795130823208768f;  // 18/pi
#pragma unroll
    for (int k = 0; k < 4; ++k) {
#pragma unroll
        for (int j = 0; j < 4; ++j) {
            float lv = (j == 0) ? Lh[k] : s[k][j - 1];
            float rv = (j == 3) ? Rh[k] : s[k][j + 1];
            float uv = (k == 0) ? Uh[j] : s[k - 1][j];
            float dv = (k == 3) ? Dh[j] : s[k + 1][j];

            float dx = __fsub_rn(lv, rv);            // 2*gx
            float dy = __fsub_rn(uv, dv);            // 2*gy
            float t1 = fmaf(dy, dy, __fmul_rn(dx, dx));
            float s2 = fmaf(t1, 0.25f, 1e-10f);      // exact power-2 scale
            float mag = __fmul_rn(__fsqrt_rn(s2), g[k][j]);

            float ax = fabsf(dx), ay = fabsf(dy);
            float mn = fminf(ax, ay);
            float mx = fmaxf(fmaxf(ax, ay), 1.17549435e-38f);   // v_max3
            float rr = mn * __builtin_amdgcn_rcpf(mx);   // ~1 ulp, scale-inv
            float t  = rr * rr;
            float u = 0.00282363896258175373077393f;     // SLEEF deg-17 odd minimax
            u = fmaf(u, t, -0.0159569028764963150024414f);
            u = fmaf(u, t,  0.0425049886107444763183594f);
            u = fmaf(u, t, -0.0748900920152664184570312f);
            u = fmaf(u, t,  0.106347933411598205566406f);
            u = fmaf(u, t, -0.142027363181114196777344f);
            u = fmaf(u, t,  0.199926957488059997558594f);
            u = fmaf(u, t, -0.333331018686294555664062f);
            float at  = fmaf(rr * t, u, rr);             // atan(rr), [0, pi/4]
            float atb = at * BINSCALE;                   // bins, [0, 4.5]

            // Quadrant fold (gx,gy never -0.0): a9 -> a18 -> copysign -> +18
            float a9  = (ay > ax)   ? __fsub_rn(9.0f,  atb) : atb;
            float a18 = (dx < 0.0f) ? __fsub_rn(18.0f, a9)  : a9;
            float as  = copysignf(a18, dy);              // v_bfi
            float obig = __fadd_rn(as, 18.0f);           // [0, 36]
            float wo1  = __builtin_amdgcn_fractf(obig);  // obig - floor(obig)
            unsigned bo = (unsigned)obig;                // 0..36 (36 = pad row)

            bool bad = fabsf(__fsub_rn(wo1, 0.5f)) >= 0.49998f;  // w/in 2e-5 of int
            float wo0 = fmaf(-wo1, mag, mag);            // (1-wo1)*mag, 1 ulp
            wo0 = bad ? 0.0f : wo0;                      // flagged: +0.0 no-op
            mycol[bo * HCOL] += wo0;                     // lane-exclusive LDS RMW
            badbits |= bad ? (1u << (k * 4 + j)) : 0u;
        }
    }

    // ---- Rare exact f64 fixup (ballot-guarded; operands from live registers)
    if (__ballot(badbits != 0)) {
#pragma unroll
        for (int k = 0; k < 4; ++k) {
#pragma unroll
            for (int j = 0; j < 4; ++j) {
                if (badbits & (1u << (k * 4 + j))) {
                    float lv = (j == 0) ? Lh[k] : s[k][j - 1];
                    float rv = (j == 3) ? Rh[k] : s[k][j + 1];
                    float uv = (k == 0) ? Uh[j] : s[k - 1][j];
                    float dv = (k == 3) ? Dh[j] : s[k + 1][j];
                    fix_pixel(lv, rv, uv, dv, g[k][j], mycol);
                }
            }
        }
    }
    asm volatile("s_waitcnt lgkmcnt(0)" ::: "memory");

    // ---- Reduction (R12-proven rotated b64 + packed accumulate): lane b
    // (<36) sums its 64-word row; banks 2*(b+k)%32 ~ free 2-way aliasing.
    float hval = 0.0f;
    if (l < NB) {
        const float2* row2 = reinterpret_cast<const float2*>(hw + l * HCOL);
        v2f tot2 = {0.0f, 0.0f};
#pragma unroll
        for (int k = 0; k < 32; ++k) {
            float2 a = row2[(k + l) & 31];
            v2f av = {a.x, a.y};
            tot2 = tot2 + av;                 // v_pk_add_f32
        }
        float tot = tot2.x + tot2.y;
        hval = __fmul_rn(tot, 1.0f / 1024.0f);   // exact power-of-2 scale
    }

    // ---- Smoothing via lane shuffles (zero pad; lane 36 holds 0)
    float hm = __shfl_up(hval, 1, 64);
    if (l == 0) hm = 0.0f;
    float hp = __shfl_down(hval, 1, 64);
    float sm = 0.0f;
    if (l < NB) {
        sm = __fadd_rn(__fadd_rn(__fmul_rn(0.33f, hm), __fmul_rn(0.34f, hval)),
                       __fmul_rn(0.33f, hp));
    }

    // ---- Argmax: f32 max butterfly + ballot + ffs (first-wins: lowest lane).
    float mv = sm;
#pragma unroll
    for (int off = 32; off > 0; off >>= 1) {
        float o = __shfl_xor(mv, off, 64);
        mv = fmaxf(mv, o);
    }
    unsigned long long msk = __ballot(sm == mv);

    if (l == 0) {
        int bi = __ffsll(msk) - 1;
        float t2 = __fdiv_rn(__fmul_rn(TWOPI_F, (float)bi), 36.0f);
        out[patch] = __fsub_rn(PI_F, t2);
    }
}

extern "C" void kernel_launch(void* const* d_in, const int* in_sizes, int n_in,
                              void* d_out, int out_size, void* d_ws, size_t ws_size,
                              hipStream_t stream) {
    const float* x = (const float*)d_in[0];
    float* out = (float*)d_out;
    float* gk10 = (float*)d_ws;   // 1024 floats = 4 KB scratch

    const int B = in_sizes[0] / NPIX;

    gk_init_kernel<<<1, 256, 0, stream>>>(gk10);
    orient_kernel<<<B / WPB, 256, 0, stream>>>(x, gk10, out);
}